// Round 2
// baseline (304.956 us; speedup 1.0000x reference)
//
#include <hip/hip_runtime.h>

// Fused attention, masked-key compaction, 6 dispatches.
// R10: full 256x256 8-phase GEMM (the verified template geometry) for
// qkvt/S/PV. R9 post-mortem: 128x256 w/ 64x64 wave-tile had only 8
// MFMA/phase -> barrier overhead dominated (MfmaUtil stuck at 23%).
// Now: BM=BN=256, BK=64, 512 thr / 8 waves (2Mx4N), wave-tile 128x64,
// 16 MFMA per phase, LDS 128KB double-buffer, counted vmcnt(4) at
// phases 4/8 only (2 half-tiles in flight across each wait), setprio
// around MFMA clusters. Staging keeps gld_lds w=16 + XOR swizzle
// (0 bank conflicts, R2/R9).
// Stagger per iter (compute t on buf0 P0-P3, t+1 on buf1 P4-P7):
//   P0: rdA0-3,B01(buf0) stg t+1.A0->buf1 | P1: rdB23 stg t+1.A1
//   P2: rdA4-7           stg t+2.B0->buf0 | P3: (regs) stg t+2.B1, VMW4
//   P4-P7 mirror on buf1, stg t+2.A0/A1->buf0, t+3.B0/B1->buf1, VMW4
// FIFO check: VMW(4) at P3 completes {t+1.B0,B1,A0,A1} before P4 reads
// buf1; VMW(4) at P7 completes t+2 before next P0 reads buf0. Last iter
// stages only t+1.A0/A1 and drains vmcnt(0) at P3.
// Tile counts: Q 128, K 4*R, Vt 4*R (R = sum ceil(npad/256), ~18) ->
// qkvt ~272 (grid-stride), S 8*pad8(R) ~160, PV 128 exact.
// Garbage rows >= npad (xc/Kc/Vt/S) are column/row-confined and never
// reach the output (softmax selects idx<counts; PV reads k<npad).
//  L1 prep / L2 gather / L5 softmax unchanged.

typedef _Float16 f16;
typedef _Float16 f16x4 __attribute__((ext_vector_type(4)));
typedef _Float16 f16x8 __attribute__((ext_vector_type(8)));
typedef float f32x4 __attribute__((ext_vector_type(4)));

#define LB256 __launch_bounds__(256)

__device__ __forceinline__ void gld16(const void* gp, void* lp) {
  __builtin_amdgcn_global_load_lds(
      (__attribute__((address_space(1))) void*)(gp),
      (__attribute__((address_space(3))) void*)(lp),
      16, 0, 0);
}

#define BAR() __builtin_amdgcn_s_barrier()
#define SCB() __builtin_amdgcn_sched_barrier(0)
#define LGK0()                                         \
  do {                                                 \
    asm volatile("s_waitcnt lgkmcnt(0)" ::: "memory"); \
    __builtin_amdgcn_sched_barrier(0);                 \
  } while (0)
#define VMW(N)                                            \
  do {                                                    \
    asm volatile("s_waitcnt vmcnt(" #N ")" ::: "memory"); \
    __builtin_amdgcn_sched_barrier(0);                    \
  } while (0)

// ds_read of A m-frags (4 x 2ks = 8 b128) into aF (compile-time idx, rule #20)
#define RD_A4(DB, IB)                                                          \
  _Pragma("unroll") for (int ii = 0; ii < 4; ++ii) _Pragma("unroll")           \
      for (int ss = 0; ss < 2; ++ss) aF[ii][ss] =                              \
          *(const f16x8*)&lds[(DB)*32768 + (wm + ((IB) + ii) * 16 + lo) * 64 + \
                              swz + (ss ? 32 - ks0 : ks0)]
// ds_read of B n-frag pair (2 x 2ks = 4 b128)
#define RD_B2(DST, DB, JB)                                                    \
  _Pragma("unroll") for (int jj = 0; jj < 2; ++jj) _Pragma("unroll")          \
      for (int ss = 0; ss < 2; ++ss) DST[jj][ss] =                            \
          *(const f16x8*)&lds[(DB)*32768 + 16384 +                            \
                              (wn + ((JB) + jj) * 16 + lo) * 64 + swz +       \
                              (ss ? 32 - ks0 : ks0)]

// one C-quadrant (64x32 of the wave's 128x64) x K=64: 16 MFMA, setprio (T5)
#define MFMA_Q(BF, AI, BJ)                                                    \
  do {                                                                        \
    __builtin_amdgcn_s_setprio(1);                                            \
    _Pragma("unroll") for (int ii = 0; ii < 4; ++ii) _Pragma("unroll")        \
        for (int jj = 0; jj < 2; ++jj) _Pragma("unroll")                      \
            for (int ss = 0; ss < 2; ++ss)                                    \
                acc[(AI) + ii][(BJ) + jj] =                                   \
                    __builtin_amdgcn_mfma_f32_16x16x32_f16(                   \
                        aF[ii][ss], BF[jj][ss], acc[(AI) + ii][(BJ) + jj],    \
                        0, 0, 0);                                             \
    __builtin_amdgcn_s_setprio(0);                                            \
  } while (0)

// ------------------------------------------------ 256x256 8-phase GEMM body
// C[m0..+255][n0..+255] = A[256xK] * B[256xK]^T (row-major, ld in f16).
// BIAS: 0 = +bias[col], 1 = +bias[row], 2 = none. K mult of 128, K>=128.
// LDS layout per buf (32768 f16): A rows 0-255 at row*64, B at 16384+row*64.
template <typename OutT, int BIAS>
__device__ __forceinline__ void gemm256(
    f16* lds, const f16* __restrict__ A, int lda, const f16* __restrict__ B,
    int ldb, OutT* __restrict__ C, int ldc, const float* __restrict__ bias,
    float scale, int K, int m0, int n0) {
  const int tid = (int)threadIdx.x;
  const int w = tid >> 6, l = tid & 63;
  const int wm = (w >> 2) * 128;  // 0,128
  const int wn = (w & 3) * 64;    // 0,64,128,192
  const int quad = l >> 4, lo = l & 15;
  const int rl = l >> 3;
  const int scol = ((l & 7) ^ rl) * 8;
  const int swz = (quad ^ (lo & 3)) * 8;
  const int ks0 = ((lo >> 2) & 1) * 32;

  f32x4 acc[8][4] = {};
  f16x8 aF[4][2], b01[2][2], b23[2][2];

  // stage one 128-row half-tile (2 gld16/thread)
  auto stgA = [&](int db, int h, int kk2) {
#pragma unroll
    for (int q = 0; q < 2; ++q) {
      const int c8 = q * 8 + w;
      gld16(A + (long)(m0 + h * 128 + c8 * 8 + rl) * lda + kk2 + scol,
            &lds[db * 32768 + h * 8192 + c8 * 512]);
    }
  };
  auto stgB = [&](int db, int h, int kk2) {
#pragma unroll
    for (int q = 0; q < 2; ++q) {
      const int c8 = q * 8 + w;
      gld16(B + (long)(n0 + h * 128 + c8 * 8 + rl) * ldb + kk2 + scol,
            &lds[db * 32768 + 16384 + h * 8192 + c8 * 512]);
    }
  };

  // prologue: tile0 full -> buf0 (8 loads), tile1 B halves -> buf1 (4)
  stgB(0, 0, 0);
  stgB(0, 1, 0);
  stgA(0, 0, 0);
  stgA(0, 1, 0);
  stgB(1, 0, 64);
  stgB(1, 1, 64);
  VMW(4);  // drains tile0's 8; leaves tile1.B0,B1 in flight
  BAR();

  const int NH = K >> 7;  // 2 K-subtiles (64 each) per iteration
  int kk = 0;
#pragma unroll 1
  for (int it = 0; it < NH; ++it) {
    const bool last = (it == NH - 1);
    // ---- P0: t Q0 (buf0); stage t+1.A0 -> buf1
    RD_A4(0, 0);
    RD_B2(b01, 0, 0);
    stgA(1, 0, kk + 64);
    BAR();
    LGK0();
    MFMA_Q(b01, 0, 0);
    SCB();
    BAR();
    // ---- P1: t Q1; stage t+1.A1
    RD_B2(b23, 0, 2);
    stgA(1, 1, kk + 64);
    BAR();
    LGK0();
    MFMA_Q(b23, 0, 2);
    SCB();
    BAR();
    // ---- P2: t Q2 (aF <- m4-7); stage t+2.B0 -> buf0 (B free after P1)
    RD_A4(0, 4);
    if (!last) stgB(0, 0, kk + 128);
    BAR();
    LGK0();
    MFMA_Q(b23, 4, 2);
    SCB();
    BAR();
    // ---- P3: t Q3 (regs only); stage t+2.B1; wait buf1 complete
    if (!last) stgB(0, 1, kk + 128);
    BAR();
    MFMA_Q(b01, 4, 0);
    SCB();
    if (!last) {
      VMW(4);  // completes t+1.{B0,B1,A0,A1}; leaves t+2.B0,B1
    } else {
      VMW(0);  // completes t+1.A0,A1
    }
    BAR();
    // ---- P4: t+1 Q0 (buf1); stage t+2.A0 -> buf0 (A free after P2)
    RD_A4(1, 0);
    RD_B2(b01, 1, 0);
    if (!last) stgA(0, 0, kk + 128);
    BAR();
    LGK0();
    MFMA_Q(b01, 0, 0);
    SCB();
    BAR();
    // ---- P5: t+1 Q1; stage t+2.A1
    RD_B2(b23, 1, 2);
    if (!last) stgA(0, 1, kk + 128);
    BAR();
    LGK0();
    MFMA_Q(b23, 0, 2);
    SCB();
    BAR();
    // ---- P6: t+1 Q2; stage t+3.B0 -> buf1 (B free after P5)
    RD_A4(1, 4);
    if (!last) stgB(1, 0, kk + 192);
    BAR();
    LGK0();
    MFMA_Q(b23, 4, 2);
    SCB();
    BAR();
    // ---- P7: t+1 Q3 (regs only); stage t+3.B1; wait buf0 complete
    if (!last) {
      stgB(1, 1, kk + 192);
      BAR();
      MFMA_Q(b01, 4, 0);
      SCB();
      VMW(4);  // completes t+2.{B0,B1,A0,A1}; leaves t+3.B0,B1
      BAR();
    } else {
      MFMA_Q(b01, 4, 0);
      SCB();
    }
    kk += 128;
  }

  // epilogue: C/D layout col=lane&15, row=quad*4+reg
#pragma unroll
  for (int i = 0; i < 8; ++i) {
    const int rowb = m0 + wm + i * 16 + quad * 4;
#pragma unroll
    for (int j = 0; j < 4; ++j) {
      const int col = n0 + wn + j * 16 + lo;
      float bc;
      if (BIAS == 0)
        bc = bias[col];
      else
        bc = 0.f;
#pragma unroll
      for (int r = 0; r < 4; ++r) {
        const float bb = (BIAS == 1) ? bias[rowb + r] : bc;
        C[(long)(rowb + r) * ldc + col] = (OutT)(acc[i][j][r] * scale + bb);
      }
    }
  }
}

// ---------------------------------------------------------------- L1 prep
__global__ LB256 void prep(const float* __restrict__ x, const float* __restrict__ wq,
                           const float* __restrict__ wk, const float* __restrict__ wv,
                           const void* __restrict__ maskp, f16* __restrict__ xh,
                           f16* __restrict__ wh, int* __restrict__ sel,
                           int* __restrict__ counts, int* __restrict__ npad) {
  const int blk = blockIdx.x;
  const int t = threadIdx.x;
  if (blk < 11264) {
    long i = ((long)blk * 256 + t) * 4;
    const float* src;
    f16* dst;
    if (i < 8388608L) {
      src = x + i;
      dst = xh + i;
    } else {
      long j = i - 8388608L;
      int which = (int)(j >> 20);
      const float* ws = which == 0 ? wq : (which == 1 ? wk : wv);
      src = ws + (j & 1048575L);
      dst = wh + j;
    }
    float4 v = *(const float4*)src;
    f16x4 o;
    o[0] = (f16)v.x; o[1] = (f16)v.y; o[2] = (f16)v.z; o[3] = (f16)v.w;
    *(f16x4*)dst = o;
  } else {
    const int b = blk - 11264;
    __shared__ int bad;
    __shared__ int s[256];
    if (t == 0) bad = 0;
    __syncthreads();
    const int* mi = (const int*)maskp;
    int loc = 0;
    for (int i = t; i < 2048; i += 256)
      if ((unsigned)mi[i] > 1u) loc = 1;  // byte-packed bools look like big ints
    if (loc) atomicOr(&bad, 1);
    __syncthreads();
    const bool bytemode = bad != 0;
    int m[8];
    if (bytemode) {
      const unsigned char* p = (const unsigned char*)maskp + b * 2048 + t * 8;
#pragma unroll
      for (int e = 0; e < 8; ++e) m[e] = p[e] != 0;
    } else {
      const int* p = mi + b * 2048 + t * 8;
#pragma unroll
      for (int e = 0; e < 8; ++e) m[e] = p[e] != 0;
    }
    int local = 0;
#pragma unroll
    for (int e = 0; e < 8; ++e) local += m[e];
    s[t] = local;
    __syncthreads();
    for (int off = 1; off < 256; off <<= 1) {
      int v = (t >= off) ? s[t - off] : 0;
      __syncthreads();
      s[t] += v;
      __syncthreads();
    }
    int offp = s[t] - local;
#pragma unroll
    for (int e = 0; e < 8; ++e)
      if (m[e]) sel[b * 2048 + offp++] = t * 8 + e;
    if (t == 0) {
      counts[b] = s[255];
      npad[b] = ((s[255] + 127) >> 7) << 7;
    }
  }
}

// ---------------------------------------------------------------- L2 gather
__global__ LB256 void gather_x(const f16* __restrict__ xh, const int* __restrict__ sel,
                               const int* __restrict__ counts,
                               const int* __restrict__ npad, f16* __restrict__ xc) {
  const int b = blockIdx.y;
  const int np = npad[b], cnt = counts[b];
  const int t = threadIdx.x;
#pragma unroll
  for (int i = 0; i < 4; ++i) {
    const int sp = blockIdx.x * 4 + i;
    if (sp >= np) continue;
    f16* dst = xc + ((long)b * 2048 + sp) * 1024;
    if (sp >= cnt) {
      *(f16x4*)(dst + t * 4) = (f16x4){0, 0, 0, 0};
    } else {
      const f16* src = xh + ((long)b * 2048 + sel[b * 2048 + sp]) * 1024;
      *(f16x4*)(dst + t * 4) = *(const f16x4*)(src + t * 4);
    }
  }
}

// ---------------------------------------------------------------- L3 Q+K+Vt
// Q: 32m x 4n, id = n*32+m (same-m ids == m mod 8 -> same XCD).
// K: id = 128 + n*MR + r (r = flattened (b,m) over ceil(npad/256) tiles;
// MR mult 8 -> same r same XCD). Vt: id = baseV + m*MR + r.
// xc rows >= npad are poison; resulting garbage stays in never-read
// regions (see header note).
__global__ __launch_bounds__(512, 2) void qkvt8p(
    const f16* __restrict__ xh, const f16* __restrict__ xc,
    const f16* __restrict__ Wh, f16* __restrict__ Qb, f16* __restrict__ Kc,
    f16* __restrict__ Vt, const float* __restrict__ bq,
    const float* __restrict__ bk, const float* __restrict__ bv,
    const int* __restrict__ npad) {
  __shared__ __align__(16) f16 lds[65536];  // 128 KiB
  int c[5];
  c[0] = 0;
#pragma unroll
  for (int b = 0; b < 4; ++b) c[b + 1] = c[b] + ((npad[b] + 255) >> 8);
  const int R = c[4];
  const int MR = (R + 7) & ~7;
  const int baseV = 128 + 4 * MR;
  const int T = baseV + 4 * MR;
  for (int t = blockIdx.x; t < T; t += gridDim.x) {
    if (t < 128) {
      const int m = t & 31, n = t >> 5;
      gemm256<f16, 0>(lds, xh, 1024, Wh, 1024, Qb, 1024, bq, 1.f, 1024,
                      m * 256, n * 256);
    } else if (t < baseV) {
      const int u = t - 128;
      const int n = u / MR, r = u % MR;
      if (r >= R) continue;
      int b = 0;
      while (r >= c[b + 1]) ++b;
      const int m = r - c[b];
      gemm256<f16, 0>(lds, xc + (long)b * 2097152, 1024, Wh + 1048576, 1024,
                      Kc + (long)b * 2097152, 1024, bk, 1.f, 1024, m * 256,
                      n * 256);
    } else {
      const int u = t - baseV;
      const int m = u / MR, r = u % MR;
      if (r >= R) continue;
      int b = 0;
      while (r >= c[b + 1]) ++b;
      const int n = r - c[b];
      gemm256<f16, 1>(lds, Wh + 2097152, 1024, xc + (long)b * 2097152, 1024,
                      Vt + (long)b * 2097152, 2048, bv, 1.f, 1024, m * 256,
                      n * 256);
    }
  }
}

// ---------------------------------------------------------------- L4 S GEMM
// tile = (b, m in [0,8), n in [0,ceil(npad/256))); rn = flatten(b,n);
// id = m*Np + rn (Np mult 8 -> same Kc panel same XCD). S cols in
// [npad, ceil256) are garbage, never read (softmax idx<np, PV k<npad).
__global__ __launch_bounds__(512, 2) void s8p(const f16* __restrict__ Qb,
                                              const f16* __restrict__ Kc,
                                              f16* __restrict__ Sbuf,
                                              const int* __restrict__ npad) {
  __shared__ __align__(16) f16 lds[65536];
  int cv[5];
  cv[0] = 0;
#pragma unroll
  for (int b = 0; b < 4; ++b) cv[b + 1] = cv[b] + ((npad[b] + 255) >> 8);
  const int R = cv[4];
  const int Np = (R + 7) & ~7;
  const int T = 8 * Np;
  for (int t = blockIdx.x; t < T; t += gridDim.x) {
    const int m = t / Np, rn = t % Np;
    if (rn >= R) continue;
    int b = 0;
    while (rn >= cv[b + 1]) ++b;
    const int n = rn - cv[b];
    gemm256<f16, 2>(lds, Qb + (long)b * 2097152, 1024, Kc + (long)b * 2097152,
                    1024, Sbuf + (long)b * 4194304, 2048, nullptr, 0.03125f,
                    1024, m * 256, n * 256);
  }
}

// ---------------------------------------------------------------- L5 softmax
__global__ LB256 void softmax_w(f16* __restrict__ S, const int* __restrict__ counts,
                                const int* __restrict__ npad) {
  const int wv = threadIdx.x >> 6, l = threadIdx.x & 63;
  const long r = (long)blockIdx.x * 4 + wv;
  const int b = (int)(r >> 11);
  const int nv = counts[b], np = npad[b];
  f16* row = S + r * 2048;

  float v[4][8];
  bool have[4];
  float mx = -3.0e38f;
#pragma unroll
  for (int g = 0; g < 4; ++g) {
    const int idx = (g * 64 + l) * 8;
    have[g] = idx < np;
    if (have[g]) {
      f16x8 sv = *(const f16x8*)(row + idx);
#pragma unroll
      for (int e = 0; e < 8; ++e) {
        float s = (idx + e < nv) ? (float)sv[e] : -3.0e38f;
        v[g][e] = s;
        mx = fmaxf(mx, s);
      }
    } else {
#pragma unroll
      for (int e = 0; e < 8; ++e) v[g][e] = -3.0e38f;
    }
  }
#pragma unroll
  for (int off = 32; off > 0; off >>= 1) mx = fmaxf(mx, __shfl_xor(mx, off, 64));

  float sum = 0.f;
  float ev[4][8];
#pragma unroll
  for (int g = 0; g < 4; ++g)
#pragma unroll
    for (int e = 0; e < 8; ++e) {
      float t = (v[g][e] <= -1.0e38f) ? 0.f : __expf(v[g][e] - mx);
      ev[g][e] = t;
      sum += t;
    }
#pragma unroll
  for (int off = 32; off > 0; off >>= 1) sum += __shfl_xor(sum, off, 64);
  const float inv = 1.f / sum;
#pragma unroll
  for (int g = 0; g < 4; ++g) {
    if (!have[g]) continue;
    const int idx = (g * 64 + l) * 8;
    f16x8 ov;
#pragma unroll
    for (int e = 0; e < 8; ++e) ov[e] = (f16)(ev[g][e] * inv);
    *(f16x8*)(row + idx) = ov;
  }
}

// ---------------------------------------------------------------- L6 PV GEMM
// O = P @ Vt^T, K=npad[b]. tile = (b, m in [0,8), n in [0,4));
// rm = b*8+m; id = n*32+rm (same Sbuf panel == rm mod 8 -> same XCD).
// T = 128 exactly.
__global__ __launch_bounds__(512, 2) void pv8p(const f16* __restrict__ Sbuf,
                                               const f16* __restrict__ Vt,
                                               float* __restrict__ out,
                                               const int* __restrict__ npad) {
  __shared__ __align__(16) f16 lds[65536];
  for (int t = blockIdx.x; t < 128; t += gridDim.x) {
    const int n = t >> 5, rm = t & 31, b = rm >> 3, m = rm & 7;
    const int K = npad[b];
    if (K < 128) continue;
    gemm256<float, 2>(lds, Sbuf + (long)b * 4194304, 2048,
                      Vt + (long)b * 2097152, 2048, out + (long)b * 2097152,
                      1024, nullptr, 1.f, K, m * 256, n * 256);
  }
}

// ---------------------------------------------------------------- launch
extern "C" void kernel_launch(void* const* d_in, const int* in_sizes, int n_in,
                              void* d_out, int out_size, void* d_ws, size_t ws_size,
                              hipStream_t stream) {
  const float* x = (const float*)d_in[0];
  const void* mask = d_in[1];
  const float* Wq = (const float*)d_in[2];
  const float* bq = (const float*)d_in[3];
  const float* Wk = (const float*)d_in[4];
  const float* bk = (const float*)d_in[5];
  const float* Wv = (const float*)d_in[6];
  const float* bv = (const float*)d_in[7];
  float* out = (float*)d_out;

  // Workspace (f16 elems), 118 MB total (proven available in R1).
  f16* xh = (f16*)d_ws;              // 8M  [0,16MB)
  f16* xc = xh + 8388608;            // 8M  [16,32)
  f16* Wh = xc + 8388608;            // 3M  [32,38)  [Wq|Wk|Wv]
  f16* Qb = Wh + 3145728;            // 8M  [38,54)
  f16* Kc = Qb + 8388608;            // 8M  [54,70)
  f16* Vt = Kc + 8388608;            // 8M  [70,86)
  f16* Sbuf = Vt + 8388608;          // 16M [86,118)
  int* sel = (int*)(Sbuf + 16777216);
  int* counts = sel + 8192;
  int* npad = counts + 4;

  prep<<<11268, 256, 0, stream>>>(x, Wq, Wk, Wv, mask, xh, Wh, sel, counts, npad);
  gather_x<<<dim3(512, 4), 256, 0, stream>>>(xh, sel, counts, npad, xc);
  qkvt8p<<<256, 512, 0, stream>>>(xh, xc, Wh, Qb, Kc, Vt, bq, bk, bv, npad);
  s8p<<<256, 512, 0, stream>>>(Qb, Kc, Sbuf, npad);
  softmax_w<<<2048, 256, 0, stream>>>(Sbuf, counts, npad);
  pv8p<<<128, 512, 0, stream>>>(Sbuf, Vt, out, npad);
}

// Round 3
// 221.517 us; speedup vs baseline: 1.3767x; 1.3767x over previous
//
#include <hip/hip_runtime.h>

// Fused attention with masked-key compaction, 6 dispatches, dense tile enumeration
// with XCD-aware grouping. R11: revert to the R8 structure (2-barrier 128x128
// body, 4 blocks/CU) after R9/R10 deep-pipeline regressions proved the regime
// wrong (1 block/CU exposes every stall; K=1024 can't amortize 8-phase
// prologues; R10: MfmaUtil 14%, 347 TF). Only change vs R8: S and PV GEMMs
// now use the full 128x128 body (16 MFMA per frag-set) instead of the M=64
// body (8 MFMA) -> double MFMA density on ~60us of work.
// R8 lesson retained: __launch_bounds__ second arg MUST be 4 (5 forced VGPR
// 64->48 and spilled acc: WRITE 34->301MB, MfmaUtil 26->9%).
//  L1 prep:    cast x,W -> f16; per-batch mask scan (sel/counts/npad)
//  L2 gather:  xc[b][s'] = xh[b][sel[s']] (pad rows zeroed)
//  L3 qkvt:    {Q(512), K(8*MTp), Vt(8*MTp)} XCD-grouped, G=1024 @4/CU
//  L4 s128:    S = (Q Kc^T)/32, 128x128 body, Kc-panel-grouped, G=1024 @4/CU
//  L5 softmax: wave-per-row
//  L6 pv128:   O = P @ Vt^T (K=npad), 128x128 body, Sbuf-panel-grouped, G=512
// GEMM core: BK=64, global_load_lds w=16, XOR-swizzled LDS (0 conflicts, R2).
// NOTE (R7): ~70 us of wall is harness re-poison fills inside the timed window.

typedef _Float16 f16;
typedef _Float16 f16x4 __attribute__((ext_vector_type(4)));
typedef _Float16 f16x8 __attribute__((ext_vector_type(8)));
typedef float f32x4 __attribute__((ext_vector_type(4)));

#define LB256 __launch_bounds__(256)

__device__ __forceinline__ void gld16(const void* gp, void* lp) {
  __builtin_amdgcn_global_load_lds(
      (__attribute__((address_space(1))) void*)(gp),
      (__attribute__((address_space(3))) void*)(lp),
      16, 0, 0);
}

// ---------------------------------------------------------------- 128x128 GEMM body
template <typename OutT>
__device__ __forceinline__ void gemm_body(
    f16* As, f16* Bs,
    const f16* __restrict__ A, int lda, const f16* __restrict__ B, int ldb,
    OutT* __restrict__ C, int ldc,
    const float* __restrict__ bias1, const float* __restrict__ bias2, int nb1,
    int bias_row, float scale, int K, int m0, int n0) {
  const int tid = threadIdx.x;
  const int w = tid >> 6, l = tid & 63;
  const int wm = (w >> 1) * 64, wn = (w & 1) * 64;
  const int quad = l >> 4, lo = l & 15;
  const int rl = l >> 3;
  const int scol = ((l & 7) ^ rl) * 8;
  const int swz = (quad ^ (lo & 3)) * 8;
  const int ks0 = ((lo >> 2) & 1) * 32;

  f32x4 acc[4][4] = {};
  for (int kk = 0; kk < K; kk += 64) {
#pragma unroll
    for (int r = 0; r < 4; ++r) {
      const int c8 = r * 4 + w;
      const int row = c8 * 8 + rl;
      gld16(A + (long)(m0 + row) * lda + kk + scol, &As[c8 * 512]);
      gld16(B + (long)(n0 + row) * ldb + kk + scol, &Bs[c8 * 512]);
    }
    __syncthreads();
#pragma unroll
    for (int ks = 0; ks < 2; ++ks) {
      const int kso = ks ? (32 - ks0) : ks0;
      f16x8 af[4], bf[4];
#pragma unroll
      for (int i = 0; i < 4; ++i)
        af[i] = *(const f16x8*)&As[(wm + i * 16 + lo) * 64 + swz + kso];
#pragma unroll
      for (int j = 0; j < 4; ++j)
        bf[j] = *(const f16x8*)&Bs[(wn + j * 16 + lo) * 64 + swz + kso];
#pragma unroll
      for (int i = 0; i < 4; ++i)
#pragma unroll
        for (int j = 0; j < 4; ++j)
          acc[i][j] = __builtin_amdgcn_mfma_f32_16x16x32_f16(af[i], bf[j],
                                                             acc[i][j], 0, 0, 0);
    }
    __syncthreads();
  }
#pragma unroll
  for (int i = 0; i < 4; ++i) {
    const int rowb = m0 + wm + i * 16 + quad * 4;
#pragma unroll
    for (int j = 0; j < 4; ++j) {
      const int col = n0 + wn + j * 16 + lo;
      float bc = 0.f;
      if (bias1 && !bias_row) bc = (col < nb1) ? bias1[col] : bias2[col - nb1];
#pragma unroll
      for (int r = 0; r < 4; ++r) {
        float bv = bias_row ? bias1[rowb + r] : bc;
        C[(long)(rowb + r) * ldc + col] = (OutT)(acc[i][j][r] * scale + bv);
      }
    }
  }
}

// ---------------------------------------------------------------- L1 prep
__global__ LB256 void prep(const float* __restrict__ x, const float* __restrict__ wq,
                           const float* __restrict__ wk, const float* __restrict__ wv,
                           const void* __restrict__ maskp, f16* __restrict__ xh,
                           f16* __restrict__ wh, int* __restrict__ sel,
                           int* __restrict__ counts, int* __restrict__ npad) {
  const int blk = blockIdx.x;
  const int t = threadIdx.x;
  if (blk < 11264) {
    long i = ((long)blk * 256 + t) * 4;
    const float* src;
    f16* dst;
    if (i < 8388608L) {
      src = x + i;
      dst = xh + i;
    } else {
      long j = i - 8388608L;
      int which = (int)(j >> 20);
      const float* ws = which == 0 ? wq : (which == 1 ? wk : wv);
      src = ws + (j & 1048575L);
      dst = wh + j;
    }
    float4 v = *(const float4*)src;
    f16x4 o;
    o[0] = (f16)v.x; o[1] = (f16)v.y; o[2] = (f16)v.z; o[3] = (f16)v.w;
    *(f16x4*)dst = o;
  } else {
    const int b = blk - 11264;
    __shared__ int bad;
    __shared__ int s[256];
    if (t == 0) bad = 0;
    __syncthreads();
    const int* mi = (const int*)maskp;
    int loc = 0;
    for (int i = t; i < 2048; i += 256)
      if ((unsigned)mi[i] > 1u) loc = 1;  // byte-packed bools look like big ints
    if (loc) atomicOr(&bad, 1);
    __syncthreads();
    const bool bytemode = bad != 0;
    int m[8];
    if (bytemode) {
      const unsigned char* p = (const unsigned char*)maskp + b * 2048 + t * 8;
#pragma unroll
      for (int e = 0; e < 8; ++e) m[e] = p[e] != 0;
    } else {
      const int* p = mi + b * 2048 + t * 8;
#pragma unroll
      for (int e = 0; e < 8; ++e) m[e] = p[e] != 0;
    }
    int local = 0;
#pragma unroll
    for (int e = 0; e < 8; ++e) local += m[e];
    s[t] = local;
    __syncthreads();
    for (int off = 1; off < 256; off <<= 1) {
      int v = (t >= off) ? s[t - off] : 0;
      __syncthreads();
      s[t] += v;
      __syncthreads();
    }
    int offp = s[t] - local;
#pragma unroll
    for (int e = 0; e < 8; ++e)
      if (m[e]) sel[b * 2048 + offp++] = t * 8 + e;
    if (t == 0) {
      counts[b] = s[255];
      npad[b] = ((s[255] + 127) >> 7) << 7;
    }
  }
}

// ---------------------------------------------------------------- L2 gather
__global__ LB256 void gather_x(const f16* __restrict__ xh, const int* __restrict__ sel,
                               const int* __restrict__ counts,
                               const int* __restrict__ npad, f16* __restrict__ xc) {
  const int b = blockIdx.y;
  const int np = npad[b], cnt = counts[b];
  const int t = threadIdx.x;
#pragma unroll
  for (int i = 0; i < 4; ++i) {
    const int sp = blockIdx.x * 4 + i;
    if (sp >= np) continue;
    f16* dst = xc + ((long)b * 2048 + sp) * 1024;
    if (sp >= cnt) {
      *(f16x4*)(dst + t * 4) = (f16x4){0, 0, 0, 0};
    } else {
      const f16* src = xh + ((long)b * 2048 + sel[b * 2048 + sp]) * 1024;
      *(f16x4*)(dst + t * 4) = *(const f16x4*)(src + t * 4);
    }
  }
}

// ---------------------------------------------------------------- L3 Q+K+Vt (XCD-grouped)
// Q tiles [0,512): id = n*64 + m -> the 8 n-tiles sharing A-rows m have ids = m
// (mod 8) -> same XCD L2. K/Vt: per-batch row-tiles flattened to r in [0,rowsK),
// padded to MTp (mult of 8); K id = 512 + n*MTp + r; Vt id = base2 + m*MTp + r.
__global__ __launch_bounds__(256, 4) void qkvt_gemm(
    const f16* __restrict__ xh, const f16* __restrict__ xc,
    const f16* __restrict__ Wh, f16* __restrict__ Qb, f16* __restrict__ Kc,
    f16* __restrict__ Vt, const float* __restrict__ bq,
    const float* __restrict__ bk, const float* __restrict__ bv,
    const int* __restrict__ npad) {
  __shared__ __align__(16) f16 As[128 * 64];
  __shared__ __align__(16) f16 Bs[128 * 64];
  int cum[5];
  cum[0] = 0;
#pragma unroll
  for (int b = 0; b < 4; ++b) cum[b + 1] = cum[b] + (npad[b] >> 7);
  const int rowsK = cum[4];
  const int MTp = (rowsK + 7) & ~7;
  const int base2 = 512 + 8 * MTp;
  const int T = base2 + 8 * MTp;

  for (int tile = blockIdx.x; tile < T; tile += gridDim.x) {
    if (tile < 512) {
      const int m = tile & 63, n = tile >> 6;
      gemm_body<f16>(As, Bs, xh, 1024, Wh, 1024, Qb, 1024, bq, bq, 1 << 30, 0,
                     1.0f, 1024, m * 128, n * 128);
    } else if (tile < base2) {
      const int u = tile - 512;
      const int n = u / MTp, r = u % MTp;
      if (r >= rowsK) continue;
      int b = 0;
      while (r >= cum[b + 1]) ++b;
      const int m = r - cum[b];
      gemm_body<f16>(As, Bs, xc + (long)b * 2048 * 1024, 1024, Wh + 1048576, 1024,
                     Kc + (long)b * 2048 * 1024, 1024, bk, bk, 1 << 30, 0, 1.0f,
                     1024, m * 128, n * 128);
    } else {
      const int u = tile - base2;
      const int m = u / MTp, r = u % MTp;
      if (r >= rowsK) continue;
      int b = 0;
      while (r >= cum[b + 1]) ++b;
      const int n = r - cum[b];
      gemm_body<f16>(As, Bs, Wh + 2097152, 1024, xc + (long)b * 2048 * 1024, 1024,
                     Vt + (long)b * 1024 * 2048, 2048, bv, bv, 0, 1, 1.0f, 1024,
                     m * 128, n * 128);
    }
  }
}

// ---------------------------------------------------------------- L4 S GEMM (128x128)
// Group by shared Kc panel (each Kc n-tile is read by 16 m-tiles): flatten (b,n)
// to rn in [0,rowsN), pad to Np (mult of 8); id = m*Np + rn -> same rn same XCD.
__global__ __launch_bounds__(256, 4) void s_gemm128(
    const f16* __restrict__ Qb, const f16* __restrict__ Kc, f16* __restrict__ Sbuf,
    const int* __restrict__ npad) {
  __shared__ __align__(16) f16 As[128 * 64];
  __shared__ __align__(16) f16 Bs[128 * 64];
  int cum[5];
  cum[0] = 0;
#pragma unroll
  for (int b = 0; b < 4; ++b) cum[b + 1] = cum[b] + (npad[b] >> 7);
  const int rowsN = cum[4];
  const int Np = (rowsN + 7) & ~7;
  const int T = 16 * Np;

  for (int tile = blockIdx.x; tile < T; tile += gridDim.x) {
    const int m = tile / Np, rn = tile % Np;
    if (rn >= rowsN) continue;
    int b = 0;
    while (rn >= cum[b + 1]) ++b;
    const int n = rn - cum[b];
    gemm_body<f16>(As, Bs, Qb + (long)b * 2048 * 1024, 1024,
                   Kc + (long)b * 2048 * 1024, 1024,
                   Sbuf + (long)b * 2048 * 2048, 2048, nullptr, nullptr, 0, 0,
                   0.03125f, 1024, m * 128, n * 128);
  }
}

// ---------------------------------------------------------------- L5 softmax (wave-per-row)
__global__ LB256 void softmax_w(f16* __restrict__ S, const int* __restrict__ counts,
                                const int* __restrict__ npad) {
  const int wv = threadIdx.x >> 6, l = threadIdx.x & 63;
  const long r = (long)blockIdx.x * 4 + wv;
  const int b = (int)(r >> 11);
  const int nv = counts[b], np = npad[b];
  f16* row = S + r * 2048;

  float v[4][8];
  bool have[4];
  float mx = -3.0e38f;
#pragma unroll
  for (int g = 0; g < 4; ++g) {
    const int idx = (g * 64 + l) * 8;
    have[g] = idx < np;
    if (have[g]) {
      f16x8 sv = *(const f16x8*)(row + idx);
#pragma unroll
      for (int e = 0; e < 8; ++e) {
        float s = (idx + e < nv) ? (float)sv[e] : -3.0e38f;
        v[g][e] = s;
        mx = fmaxf(mx, s);
      }
    } else {
#pragma unroll
      for (int e = 0; e < 8; ++e) v[g][e] = -3.0e38f;
    }
  }
#pragma unroll
  for (int off = 32; off > 0; off >>= 1) mx = fmaxf(mx, __shfl_xor(mx, off, 64));

  float sum = 0.f;
  float ev[4][8];
#pragma unroll
  for (int g = 0; g < 4; ++g)
#pragma unroll
    for (int e = 0; e < 8; ++e) {
      float t = (v[g][e] <= -1.0e38f) ? 0.f : __expf(v[g][e] - mx);
      ev[g][e] = t;
      sum += t;
    }
#pragma unroll
  for (int off = 32; off > 0; off >>= 1) sum += __shfl_xor(sum, off, 64);
  const float inv = 1.f / sum;
#pragma unroll
  for (int g = 0; g < 4; ++g) {
    if (!have[g]) continue;
    const int idx = (g * 64 + l) * 8;
    f16x8 ov;
#pragma unroll
    for (int e = 0; e < 8; ++e) ov[e] = (f16)(ev[g][e] * inv);
    *(f16x8*)(row + idx) = ov;
  }
}

// ---------------------------------------------------------------- L6 PV GEMM (128x128)
// O = P @ Vt^T (K=npad). rm = b*16+m in [0,64); id = n*64 + rm: the 8 n-tiles
// sharing Sbuf rows (b,m) have ids = rm (mod 8) -> same XCD. T = 512 exact.
__global__ __launch_bounds__(256, 4) void pv_gemm128(
    const f16* __restrict__ Sbuf, const f16* __restrict__ Vt,
    float* __restrict__ out, const int* __restrict__ npad) {
  __shared__ __align__(16) f16 As[128 * 64];
  __shared__ __align__(16) f16 Bs[128 * 64];
  const int tile = blockIdx.x;
  const int n = tile >> 6, rm = tile & 63, b = rm >> 4, m = rm & 15;
  gemm_body<float>(As, Bs, Sbuf + (long)b * 2048 * 2048, 2048,
                   Vt + (long)b * 1024 * 2048, 2048, out + (long)b * 2048 * 1024,
                   1024, nullptr, nullptr, 0, 0, 1.0f, npad[b], m * 128, n * 128);
}

// ---------------------------------------------------------------- launch
extern "C" void kernel_launch(void* const* d_in, const int* in_sizes, int n_in,
                              void* d_out, int out_size, void* d_ws, size_t ws_size,
                              hipStream_t stream) {
  const float* x = (const float*)d_in[0];
  const void* mask = d_in[1];
  const float* Wq = (const float*)d_in[2];
  const float* bq = (const float*)d_in[3];
  const float* Wk = (const float*)d_in[4];
  const float* bk = (const float*)d_in[5];
  const float* Wv = (const float*)d_in[6];
  const float* bv = (const float*)d_in[7];
  float* out = (float*)d_out;

  // Workspace (f16 elems), 118 MB total (proven available in R1).
  f16* xh = (f16*)d_ws;              // 8M  [0,16MB)
  f16* xc = xh + 8388608;            // 8M  [16,32)
  f16* Wh = xc + 8388608;            // 3M  [32,38)  [Wq|Wk|Wv]
  f16* Qb = Wh + 3145728;            // 8M  [38,54)
  f16* Kc = Qb + 8388608;            // 8M  [54,70)
  f16* Vt = Kc + 8388608;            // 8M  [70,86)
  f16* Sbuf = Vt + 8388608;          // 16M [86,118)
  int* sel = (int*)(Sbuf + 16777216);
  int* counts = sel + 8192;
  int* npad = counts + 4;

  prep<<<11268, 256, 0, stream>>>(x, Wq, Wk, Wv, mask, xh, Wh, sel, counts, npad);
  gather_x<<<dim3(512, 4), 256, 0, stream>>>(xh, sel, counts, npad, xc);
  qkvt_gemm<<<1024, 256, 0, stream>>>(xh, xc, Wh, Qb, Kc, Vt, bq, bk, bv, npad);
  s_gemm128<<<1024, 256, 0, stream>>>(Qb, Kc, Sbuf, npad);
  softmax_w<<<2048, 256, 0, stream>>>(Sbuf, counts, npad);
  pv_gemm128<<<512, 256, 0, stream>>>(Sbuf, Vt, out, npad);
}